// Round 5
// baseline (490.650 us; speedup 1.0000x reference)
//
#include <hip/hip_runtime.h>

// SelfAttentionFusion: 3D window attention, WS=4, N=64 tokens/window, C=128, 4 heads x 32.
// 4096 windows, one 256-thread block each. fp32 I/O; bf16 internally for MFMA.
// Round 5: round-4 register-resident structure (Q/K/V/P via ds_bpermute quad-exchange,
// 32 KB LDS, 4 barriers) with verified manual RNE f32->bf16 packing everywhere.

typedef __attribute__((ext_vector_type(8))) short bf16x8;
typedef __attribute__((ext_vector_type(4))) float f32x4;

__device__ __forceinline__ unsigned short f2b(float f) {
    union { float f; unsigned int i; } v; v.f = f;
    unsigned int i = v.i;
    return (unsigned short)((i + 0x7FFFu + ((i >> 16) & 1u)) >> 16);
}
// pack bf16(a) in low16, bf16(b) in high16 (verified manual RNE)
__device__ __forceinline__ unsigned int pkman(float a, float b) {
    return ((unsigned int)f2b(b) << 16) | (unsigned int)f2b(a);
}

union U8 { bf16x8 v; unsigned int u[4]; };

// Quad-exchange: C-frags (lo: rows 0..15, hi: rows 16..31 of a 32-row block,
// row = 16*(hi) + 4*quad + g, col = lane&15) -> A/B-frag (m/n = lane&15 = col,
// element j holds row k = 8*quad + j).
__device__ __forceinline__ bf16x8 xfrag(const f32x4 lo, const f32x4 hi,
                                        int aA, int aB, bool hiq) {
    unsigned int l0 = pkman(lo[0], lo[1]), l1 = pkman(lo[2], lo[3]);
    unsigned int h0 = pkman(hi[0], hi[1]), h1 = pkman(hi[2], hi[3]);
    U8 r;
    unsigned int tl, th;
    tl = (unsigned int)__builtin_amdgcn_ds_bpermute(aA, (int)l0);
    th = (unsigned int)__builtin_amdgcn_ds_bpermute(aA, (int)h0);
    r.u[0] = hiq ? th : tl;
    tl = (unsigned int)__builtin_amdgcn_ds_bpermute(aA, (int)l1);
    th = (unsigned int)__builtin_amdgcn_ds_bpermute(aA, (int)h1);
    r.u[1] = hiq ? th : tl;
    tl = (unsigned int)__builtin_amdgcn_ds_bpermute(aB, (int)l0);
    th = (unsigned int)__builtin_amdgcn_ds_bpermute(aB, (int)h0);
    r.u[2] = hiq ? th : tl;
    tl = (unsigned int)__builtin_amdgcn_ds_bpermute(aB, (int)l1);
    th = (unsigned int)__builtin_amdgcn_ds_bpermute(aB, (int)h1);
    r.u[3] = hiq ? th : tl;
    return r.v;
}

// ---- workspace layout ----
// wsW (ushort): fragment-ordered bf16 weights, group = 64 lanes x 8 elems per tile
//   conv [0,512) trans [512,1024) qkv [1024,7168) (q rows prescaled) proj [7168,9216)
// wsB (float @byte 147456): bias C-frags for S^T: [h][mt][nt][lane]*4
#define WSB_BYTE_OFF 147456

__global__ __launch_bounds__(256) void prep_kernel(
    const float* __restrict__ conv_w, const float* __restrict__ trans_w,
    const float* __restrict__ qkv_w, const float* __restrict__ proj_w,
    const float* __restrict__ btab, const int* __restrict__ ridx,
    unsigned short* __restrict__ wsW, float* __restrict__ wsB)
{
    int id = blockIdx.x * 256 + threadIdx.x;
    if (id < 9216) {
        int lane = id & 63;
        int colr = lane & 15, quad = lane >> 4;
        const float* src;
        float scale = 1.0f;
        if (id < 512) {
            int tile = id >> 6; int rt = tile >> 1, kt = tile & 1;
            src = conv_w + (rt * 16 + colr) * 64 + kt * 32 + quad * 8;
        } else if (id < 1024) {
            int tile = (id - 512) >> 6; int rt = tile >> 1, kt = tile & 1;
            src = trans_w + (rt * 16 + colr) * 64 + kt * 32 + quad * 8;
        } else if (id < 7168) {
            int tile = (id - 1024) >> 6; int rt = tile >> 2, kt = tile & 3;
            int r = rt * 16 + colr;
            src = qkv_w + r * 128 + kt * 32 + quad * 8;
            if (r < 128) scale = 0.17677669529663689f;  // fold hd^-0.5 into q weights
        } else {
            int tile = (id - 7168) >> 6; int rt = tile >> 2, kt = tile & 3;
            src = proj_w + (rt * 16 + colr) * 128 + kt * 32 + quad * 8;
        }
        bf16x8 r;
#pragma unroll
        for (int j = 0; j < 8; ++j) r[j] = (short)f2b(src[j] * scale);
        *reinterpret_cast<bf16x8*>(wsW + id * 8) = r;
    } else if (id < 13312) {
        int i = id - 9216;                        // 0..4095
        int h = i >> 10, mt = (i >> 8) & 3, nt = (i >> 6) & 3, lane = i & 63;
        int colr = lane & 15, quad = lane >> 4;
        f32x4 o;
#pragma unroll
        for (int g = 0; g < 4; ++g) {
            int n = nt * 16 + colr;               // query token
            int m = mt * 16 + quad * 4 + g;       // key token (S^T row)
            o[g] = btab[ridx[n * 64 + m] * 4 + h];
        }
        *reinterpret_cast<f32x4*>(wsB + i * 4) = o;
    }
}

// ---- LDS: 2 regions of 8192 ushorts (32 KB) ----
// A [0,8192):     XIN[t][128] -> AO[t][128]
// B [8192,16384): X[t][128]   -> FU[c][64] (fp32)
#define REG_A 0
#define REG_B 8192

__device__ __forceinline__ int idx128(int base, int t, int c) {
    int swz = ((c >> 3) ^ (t & 15)) & 15;
    return base + t * 128 + (swz << 3) + (c & 7);
}
__device__ __forceinline__ int idxfu(int c, int t) {
    int swz = ((t >> 2) ^ (c & 15)) & 15;
    return c * 64 + (swz << 2) + (t & 3);
}

__global__ __launch_bounds__(256, 4) void win_attn_kernel(
    const float* __restrict__ cfeat,
    const float* __restrict__ tfeat,
    const float* __restrict__ conv_b,
    const float* __restrict__ trans_b,
    const float* __restrict__ qkv_b,
    const float* __restrict__ proj_b,
    const unsigned short* __restrict__ wsW,
    const float* __restrict__ wsB,
    float* __restrict__ out)
{
    __shared__ unsigned short smem[16384];  // 32 KB
    float* fuf = reinterpret_cast<float*>(&smem[REG_B]);

    const int tid  = threadIdx.x;
    const int lane = tid & 63;
    const int wv   = tid >> 6;
    const int col  = lane & 15;
    const int quad = lane >> 4;

    // XCD swizzle: consecutive same-XCD dispatch slots get consecutive wx -> L2 sharing
    int b   = blockIdx.x;
    int wid = ((b & 7) << 9) | (b >> 3);
    int wz = wid >> 8, wy = (wid >> 4) & 15, wx = wid & 15;
    const int vbase = wz * 16384 + wy * 256 + wx * 4;

    // ---- S1: global fp32 -> bf16 XIN[t][cc] (A) via b128 writes ----
#pragma unroll
    for (int it = 0; it < 4; ++it) {
        int id = tid + (it << 8);          // 0..1023
        int cg = id >> 6;                  // 16 chunks (8 conv, 8 trans)
        int t  = id & 63;
        int inp = cg >> 3;
        int c0  = (cg & 7) << 3;
        const float* src = (inp ? tfeat : cfeat) + (size_t)c0 * 262144 + vbase
                         + ((t >> 4) << 12) + (((t >> 2) & 3) << 6) + (t & 3);
        float f[8];
#pragma unroll
        for (int j = 0; j < 8; ++j) f[j] = src[(size_t)j * 262144];
        U8 r;
#pragma unroll
        for (int j = 0; j < 4; ++j) r.u[j] = pkman(f[2 * j], f[2 * j + 1]);
        *reinterpret_cast<bf16x8*>(&smem[idx128(REG_A, t, inp * 64 + c0)]) = r.v;
    }
    __syncthreads();                                   // [1]

    // ---- S2: input projection -> X[t][o] (B) ----
    {
        int half = wv >> 1;
        const float* bvec = half ? trans_b : conv_b;
        bf16x8 afr[4][2];
#pragma unroll
        for (int tt = 0; tt < 4; ++tt)
#pragma unroll
            for (int kt = 0; kt < 2; ++kt)
                afr[tt][kt] = *reinterpret_cast<const bf16x8*>(
                    &smem[idx128(REG_A, tt * 16 + col, half * 64 + kt * 32 + quad * 8)]);
#pragma unroll
        for (int otl = 0; otl < 2; ++otl) {
            int rt  = (wv & 1) * 2 + otl;
            int row = rt * 16 + col;
            bf16x8 bfr[2];
#pragma unroll
            for (int kt = 0; kt < 2; ++kt)
                bfr[kt] = *reinterpret_cast<const bf16x8*>(
                    wsW + (half * 512 + (rt * 2 + kt) * 64 + lane) * 8);
            float bias = bvec[row];
            int oc = half * 64 + row;
#pragma unroll
            for (int tt = 0; tt < 4; ++tt) {
                f32x4 acc = {0.f, 0.f, 0.f, 0.f};
#pragma unroll
                for (int kt = 0; kt < 2; ++kt)
                    acc = __builtin_amdgcn_mfma_f32_16x16x32_bf16(afr[tt][kt], bfr[kt], acc, 0, 0, 0);
                unsigned int pA = pkman(acc[0] + bias, acc[1] + bias);
                unsigned int pB = pkman(acc[2] + bias, acc[3] + bias);
                int t0 = tt * 16 + quad * 4;
                smem[idx128(REG_B, t0 + 0, oc)] = (unsigned short)(pA & 0xffff);
                smem[idx128(REG_B, t0 + 1, oc)] = (unsigned short)(pA >> 16);
                smem[idx128(REG_B, t0 + 2, oc)] = (unsigned short)(pB & 0xffff);
                smem[idx128(REG_B, t0 + 3, oc)] = (unsigned short)(pB >> 16);
            }
        }
    }
    __syncthreads();                                   // [2]

    // ---- S3/S4: per-head (wave=head) register-resident attention ----
    {
        const int h = wv;
        const int aA = ((((2 * quad) & 3) << 4) | col) << 2;
        const int aB = ((((2 * quad + 1) & 3) << 4) | col) << 2;
        const bool hiq = quad >= 2;

        // hoisted biases
        float4 qb4[2], kb4[2]; float vb2[2];
#pragma unroll
        for (int dt = 0; dt < 2; ++dt) {
            float4 q = *reinterpret_cast<const float4*>(qkv_b + h * 32 + dt * 16 + quad * 4);
            q.x *= 0.17677669529663689f; q.y *= 0.17677669529663689f;
            q.z *= 0.17677669529663689f; q.w *= 0.17677669529663689f;
            qb4[dt] = q;
            kb4[dt] = *reinterpret_cast<const float4*>(qkv_b + 128 + h * 32 + dt * 16 + quad * 4);
            vb2[dt] = qkv_b[256 + h * 32 + dt * 16 + col];
        }

        bf16x8 qb[4], kb[4], vfr[2][2];

        // V^T: D[token][d] = mfma(A=X tokens, B=Wv rows d) -> exchange -> vfr[dt][kt]
#pragma unroll
        for (int dt = 0; dt < 2; ++dt) {
            bf16x8 w[4];
#pragma unroll
            for (int kt = 0; kt < 4; ++kt)
                w[kt] = *reinterpret_cast<const bf16x8*>(
                    wsW + (1024 + ((16 + 2 * h + dt) * 4 + kt) * 64 + lane) * 8);
            f32x4 vt[4];
#pragma unroll
            for (int tt = 0; tt < 4; ++tt) {
                bf16x8 a[4];
#pragma unroll
                for (int kt = 0; kt < 4; ++kt)
                    a[kt] = *reinterpret_cast<const bf16x8*>(
                        &smem[idx128(REG_B, tt * 16 + col, kt * 32 + quad * 8)]);
                f32x4 acc = {0.f, 0.f, 0.f, 0.f};
#pragma unroll
                for (int kt = 0; kt < 4; ++kt)
                    acc = __builtin_amdgcn_mfma_f32_16x16x32_bf16(a[kt], w[kt], acc, 0, 0, 0);
#pragma unroll
                for (int g = 0; g < 4; ++g) acc[g] += vb2[dt];
                vt[tt] = acc;
            }
            vfr[dt][0] = xfrag(vt[0], vt[1], aA, aB, hiq);
            vfr[dt][1] = xfrag(vt[2], vt[3], aA, aB, hiq);
        }

        // Q^T: D[d][token] = mfma(A=Wq rows d, B=X tokens) -> exchange -> qb[nt]
#pragma unroll
        for (int nt = 0; nt < 4; ++nt) {
            bf16x8 a[4];
#pragma unroll
            for (int kt = 0; kt < 4; ++kt)
                a[kt] = *reinterpret_cast<const bf16x8*>(
                    &smem[idx128(REG_B, nt * 16 + col, kt * 32 + quad * 8)]);
            f32x4 qa[2];
#pragma unroll
            for (int dt = 0; dt < 2; ++dt) {
                bf16x8 w[4];
#pragma unroll
                for (int kt = 0; kt < 4; ++kt)
                    w[kt] = *reinterpret_cast<const bf16x8*>(
                        wsW + (1024 + ((2 * h + dt) * 4 + kt) * 64 + lane) * 8);
                f32x4 acc = {0.f, 0.f, 0.f, 0.f};
#pragma unroll
                for (int kt = 0; kt < 4; ++kt)
                    acc = __builtin_amdgcn_mfma_f32_16x16x32_bf16(w[kt], a[kt], acc, 0, 0, 0);
                acc[0] += qb4[dt].x; acc[1] += qb4[dt].y;
                acc[2] += qb4[dt].z; acc[3] += qb4[dt].w;
                qa[dt] = acc;
            }
            qb[nt] = xfrag(qa[0], qa[1], aA, aB, hiq);
        }

        // K^T -> kb[mt]
#pragma unroll
        for (int mt = 0; mt < 4; ++mt) {
            bf16x8 a[4];
#pragma unroll
            for (int kt = 0; kt < 4; ++kt)
                a[kt] = *reinterpret_cast<const bf16x8*>(
                    &smem[idx128(REG_B, mt * 16 + col, kt * 32 + quad * 8)]);
            f32x4 ka[2];
#pragma unroll
            for (int dt = 0; dt < 2; ++dt) {
                bf16x8 w[4];
#pragma unroll
                for (int kt = 0; kt < 4; ++kt)
                    w[kt] = *reinterpret_cast<const bf16x8*>(
                        wsW + (1024 + ((8 + 2 * h + dt) * 4 + kt) * 64 + lane) * 8);
                f32x4 acc = {0.f, 0.f, 0.f, 0.f};
#pragma unroll
                for (int kt = 0; kt < 4; ++kt)
                    acc = __builtin_amdgcn_mfma_f32_16x16x32_bf16(w[kt], a[kt], acc, 0, 0, 0);
                acc[0] += kb4[dt].x; acc[1] += kb4[dt].y;
                acc[2] += kb4[dt].z; acc[3] += kb4[dt].w;
                ka[dt] = acc;
            }
            kb[mt] = xfrag(ka[0], ka[1], aA, aB, hiq);
        }

        // S^T (bias as C-init) -> exp -> normalize -> exchange -> PV -> AO (A)
#pragma unroll
        for (int nt = 0; nt < 4; ++nt) {
            f32x4 st[4];
#pragma unroll
            for (int mt = 0; mt < 4; ++mt) {
                f32x4 binit = *reinterpret_cast<const f32x4*>(
                    wsB + ((((h * 4 + mt) * 4 + nt) * 64 + lane) << 2));
                st[mt] = __builtin_amdgcn_mfma_f32_16x16x32_bf16(kb[mt], qb[nt], binit, 0, 0, 0);
            }
            float sm = 0.f;
#pragma unroll
            for (int mt = 0; mt < 4; ++mt)
#pragma unroll
                for (int g = 0; g < 4; ++g) {
                    st[mt][g] = __expf(fminf(st[mt][g], 80.f));
                    sm += st[mt][g];
                }
            sm += __shfl_xor(sm, 16, 64);
            sm += __shfl_xor(sm, 32, 64);
            float inv = 1.0f / sm;
#pragma unroll
            for (int mt = 0; mt < 4; ++mt)
#pragma unroll
                for (int g = 0; g < 4; ++g) st[mt][g] *= inv;
            bf16x8 pa0 = xfrag(st[0], st[1], aA, aB, hiq);
            bf16x8 pa1 = xfrag(st[2], st[3], aA, aB, hiq);
#pragma unroll
            for (int dt = 0; dt < 2; ++dt) {
                f32x4 o = {0.f, 0.f, 0.f, 0.f};
                o = __builtin_amdgcn_mfma_f32_16x16x32_bf16(pa0, vfr[dt][0], o, 0, 0, 0);
                o = __builtin_amdgcn_mfma_f32_16x16x32_bf16(pa1, vfr[dt][1], o, 0, 0, 0);
                int c  = h * 32 + dt * 16 + col;
                int t0 = nt * 16 + quad * 4;
                unsigned int pA = pkman(o[0], o[1]);
                unsigned int pB = pkman(o[2], o[3]);
                smem[idx128(REG_A, t0 + 0, c)] = (unsigned short)(pA & 0xffff);
                smem[idx128(REG_A, t0 + 1, c)] = (unsigned short)(pA >> 16);
                smem[idx128(REG_A, t0 + 2, c)] = (unsigned short)(pB & 0xffff);
                smem[idx128(REG_A, t0 + 3, c)] = (unsigned short)(pB >> 16);
            }
        }
    }
    __syncthreads();                                   // [3]

    // ---- S5: proj + fold halves + bias -> FU[c][t] fp32 (B) ----
    {
        bf16x8 afr[4][4];
#pragma unroll
        for (int tt = 0; tt < 4; ++tt)
#pragma unroll
            for (int kt = 0; kt < 4; ++kt)
                afr[tt][kt] = *reinterpret_cast<const bf16x8*>(
                    &smem[idx128(REG_A, tt * 16 + col, kt * 32 + quad * 8)]);
        int o1 = wv * 16 + col;
        int o2 = 64 + o1;
        bf16x8 b1[4], b2[4];
#pragma unroll
        for (int kt = 0; kt < 4; ++kt) {
            b1[kt] = *reinterpret_cast<const bf16x8*>(wsW + (7168 + (wv * 4 + kt) * 64 + lane) * 8);
            b2[kt] = *reinterpret_cast<const bf16x8*>(wsW + (7168 + ((4 + wv) * 4 + kt) * 64 + lane) * 8);
        }
        float pb = proj_b[o1] + proj_b[o2];
#pragma unroll
        for (int tt = 0; tt < 4; ++tt) {
            f32x4 a1 = {0.f, 0.f, 0.f, 0.f}, a2 = {0.f, 0.f, 0.f, 0.f};
#pragma unroll
            for (int kt = 0; kt < 4; ++kt) {
                a1 = __builtin_amdgcn_mfma_f32_16x16x32_bf16(afr[tt][kt], b1[kt], a1, 0, 0, 0);
                a2 = __builtin_amdgcn_mfma_f32_16x16x32_bf16(afr[tt][kt], b2[kt], a2, 0, 0, 0);
            }
            f32x4 o;
#pragma unroll
            for (int g = 0; g < 4; ++g) o[g] = a1[g] + a2[g] + pb;
            *reinterpret_cast<f32x4*>(&fuf[idxfu(o1, tt * 16 + quad * 4)]) = o;
        }
    }
    __syncthreads();                                   // [4]

    // ---- S6: out = FU + conv_feat residual, coalesced float4 ----
#pragma unroll
    for (int it = 0; it < 4; ++it) {
        int id = tid + (it << 8);       // 0..1023
        int c  = id >> 4;
        int z  = (id >> 2) & 3, y = id & 3;
        int t  = z * 16 + y * 4;
        f32x4 val = *reinterpret_cast<const f32x4*>(&fuf[idxfu(c, t)]);
        f32x4 res = *reinterpret_cast<const f32x4*>(cfeat + (size_t)c * 262144 + vbase + z * 4096 + y * 64);
        f32x4 o;
#pragma unroll
        for (int g = 0; g < 4; ++g) o[g] = val[g] + res[g];
        *reinterpret_cast<f32x4*>(out + (size_t)c * 262144 + vbase + z * 4096 + y * 64) = o;
    }
}

extern "C" void kernel_launch(void* const* d_in, const int* in_sizes, int n_in,
                              void* d_out, int out_size, void* d_ws, size_t ws_size,
                              hipStream_t stream) {
    (void)in_sizes; (void)n_in; (void)out_size; (void)ws_size;
    unsigned short* wsW = (unsigned short*)d_ws;
    float* wsB = (float*)((char*)d_ws + WSB_BYTE_OFF);

    prep_kernel<<<dim3(52), dim3(256), 0, stream>>>(
        (const float*)d_in[2],  // conv_w
        (const float*)d_in[4],  // trans_w
        (const float*)d_in[6],  // qkv_w
        (const float*)d_in[8],  // proj_w
        (const float*)d_in[10], // rel_bias_table
        (const int*)d_in[11],   // rel_index
        wsW, wsB);

    win_attn_kernel<<<dim3(4096), dim3(256), 0, stream>>>(
        (const float*)d_in[0],  // conv_feat
        (const float*)d_in[1],  // transformer_feat
        (const float*)d_in[3],  // conv_b
        (const float*)d_in[5],  // trans_b
        (const float*)d_in[7],  // qkv_b
        (const float*)d_in[9],  // proj_b
        wsW, wsB,
        (float*)d_out);
}

// Round 6
// 363.383 us; speedup vs baseline: 1.3502x; 1.3502x over previous
//
#include <hip/hip_runtime.h>

// SelfAttentionFusion: 3D window attention, WS=4, N=64 tokens/window, C=128, 4 heads x 32.
// 4096 windows, one 256-thread block each. fp32 I/O; bf16 internally for MFMA.
// Round 6: round-5 register-resident structure; launch_bounds(256,3) to stop the
// 64-VGPR spill cliff; V weights hoisted; Q/K share X-fragment loads.

typedef __attribute__((ext_vector_type(8))) short bf16x8;
typedef __attribute__((ext_vector_type(4))) float f32x4;

__device__ __forceinline__ unsigned short f2b(float f) {
    union { float f; unsigned int i; } v; v.f = f;
    unsigned int i = v.i;
    return (unsigned short)((i + 0x7FFFu + ((i >> 16) & 1u)) >> 16);
}
// pack bf16(a) in low16, bf16(b) in high16 (verified manual RNE)
__device__ __forceinline__ unsigned int pkman(float a, float b) {
    return ((unsigned int)f2b(b) << 16) | (unsigned int)f2b(a);
}

union U8 { bf16x8 v; unsigned int u[4]; };

// Quad-exchange: C-frags (lo: rows 0..15, hi: rows 16..31 of a 32-row block,
// row = 16*(hi) + 4*quad + g, col = lane&15) -> A/B-frag (m/n = lane&15,
// element j holds row k = 8*quad + j). HW-verified (round 5 passed).
__device__ __forceinline__ bf16x8 xfrag(const f32x4 lo, const f32x4 hi,
                                        int aA, int aB, bool hiq) {
    unsigned int l0 = pkman(lo[0], lo[1]), l1 = pkman(lo[2], lo[3]);
    unsigned int h0 = pkman(hi[0], hi[1]), h1 = pkman(hi[2], hi[3]);
    U8 r;
    unsigned int tl, th;
    tl = (unsigned int)__builtin_amdgcn_ds_bpermute(aA, (int)l0);
    th = (unsigned int)__builtin_amdgcn_ds_bpermute(aA, (int)h0);
    r.u[0] = hiq ? th : tl;
    tl = (unsigned int)__builtin_amdgcn_ds_bpermute(aA, (int)l1);
    th = (unsigned int)__builtin_amdgcn_ds_bpermute(aA, (int)h1);
    r.u[1] = hiq ? th : tl;
    tl = (unsigned int)__builtin_amdgcn_ds_bpermute(aB, (int)l0);
    th = (unsigned int)__builtin_amdgcn_ds_bpermute(aB, (int)h0);
    r.u[2] = hiq ? th : tl;
    tl = (unsigned int)__builtin_amdgcn_ds_bpermute(aB, (int)l1);
    th = (unsigned int)__builtin_amdgcn_ds_bpermute(aB, (int)h1);
    r.u[3] = hiq ? th : tl;
    return r.v;
}

// ---- workspace layout ----
// wsW (ushort): fragment-ordered bf16 weights, group = 64 lanes x 8 elems per tile
//   conv [0,512) trans [512,1024) qkv [1024,7168) (q rows prescaled) proj [7168,9216)
// wsB (float @byte 147456): bias C-frags for S^T: [h][mt][nt][lane]*4
#define WSB_BYTE_OFF 147456

__global__ __launch_bounds__(256) void prep_kernel(
    const float* __restrict__ conv_w, const float* __restrict__ trans_w,
    const float* __restrict__ qkv_w, const float* __restrict__ proj_w,
    const float* __restrict__ btab, const int* __restrict__ ridx,
    unsigned short* __restrict__ wsW, float* __restrict__ wsB)
{
    int id = blockIdx.x * 256 + threadIdx.x;
    if (id < 9216) {
        int lane = id & 63;
        int colr = lane & 15, quad = lane >> 4;
        const float* src;
        float scale = 1.0f;
        if (id < 512) {
            int tile = id >> 6; int rt = tile >> 1, kt = tile & 1;
            src = conv_w + (rt * 16 + colr) * 64 + kt * 32 + quad * 8;
        } else if (id < 1024) {
            int tile = (id - 512) >> 6; int rt = tile >> 1, kt = tile & 1;
            src = trans_w + (rt * 16 + colr) * 64 + kt * 32 + quad * 8;
        } else if (id < 7168) {
            int tile = (id - 1024) >> 6; int rt = tile >> 2, kt = tile & 3;
            int r = rt * 16 + colr;
            src = qkv_w + r * 128 + kt * 32 + quad * 8;
            if (r < 128) scale = 0.17677669529663689f;  // fold hd^-0.5 into q weights
        } else {
            int tile = (id - 7168) >> 6; int rt = tile >> 2, kt = tile & 3;
            src = proj_w + (rt * 16 + colr) * 128 + kt * 32 + quad * 8;
        }
        bf16x8 r;
#pragma unroll
        for (int j = 0; j < 8; ++j) r[j] = (short)f2b(src[j] * scale);
        *reinterpret_cast<bf16x8*>(wsW + id * 8) = r;
    } else if (id < 13312) {
        int i = id - 9216;                        // 0..4095
        int h = i >> 10, mt = (i >> 8) & 3, nt = (i >> 6) & 3, lane = i & 63;
        int colr = lane & 15, quad = lane >> 4;
        f32x4 o;
#pragma unroll
        for (int g = 0; g < 4; ++g) {
            int n = nt * 16 + colr;               // query token
            int m = mt * 16 + quad * 4 + g;       // key token (S^T row)
            o[g] = btab[ridx[n * 64 + m] * 4 + h];
        }
        *reinterpret_cast<f32x4*>(wsB + i * 4) = o;
    }
}

// ---- LDS: 2 regions of 8192 ushorts (32 KB) ----
// A [0,8192):     XIN[t][128] -> AO[t][128]
// B [8192,16384): X[t][128]   -> FU[c][64] (fp32)
#define REG_A 0
#define REG_B 8192

__device__ __forceinline__ int idx128(int base, int t, int c) {
    int swz = ((c >> 3) ^ (t & 15)) & 15;
    return base + t * 128 + (swz << 3) + (c & 7);
}
__device__ __forceinline__ int idxfu(int c, int t) {
    int swz = ((t >> 2) ^ (c & 15)) & 15;
    return c * 64 + (swz << 2) + (t & 3);
}

__global__ __launch_bounds__(256, 3) void win_attn_kernel(
    const float* __restrict__ cfeat,
    const float* __restrict__ tfeat,
    const float* __restrict__ conv_b,
    const float* __restrict__ trans_b,
    const float* __restrict__ qkv_b,
    const float* __restrict__ proj_b,
    const unsigned short* __restrict__ wsW,
    const float* __restrict__ wsB,
    float* __restrict__ out)
{
    __shared__ unsigned short smem[16384];  // 32 KB
    float* fuf = reinterpret_cast<float*>(&smem[REG_B]);

    const int tid  = threadIdx.x;
    const int lane = tid & 63;
    const int wv   = tid >> 6;
    const int col  = lane & 15;
    const int quad = lane >> 4;

    // XCD swizzle: consecutive same-XCD dispatch slots get consecutive wx -> L2 sharing
    int b   = blockIdx.x;
    int wid = ((b & 7) << 9) | (b >> 3);
    int wz = wid >> 8, wy = (wid >> 4) & 15, wx = wid & 15;
    const int vbase = wz * 16384 + wy * 256 + wx * 4;

    // ---- S1: global fp32 -> bf16 XIN[t][cc] (A) via b128 writes ----
#pragma unroll
    for (int it = 0; it < 4; ++it) {
        int id = tid + (it << 8);          // 0..1023
        int cg = id >> 6;                  // 16 chunks (8 conv, 8 trans)
        int t  = id & 63;
        int inp = cg >> 3;
        int c0  = (cg & 7) << 3;
        const float* src = (inp ? tfeat : cfeat) + (size_t)c0 * 262144 + vbase
                         + ((t >> 4) << 12) + (((t >> 2) & 3) << 6) + (t & 3);
        float f[8];
#pragma unroll
        for (int j = 0; j < 8; ++j) f[j] = src[(size_t)j * 262144];
        U8 r;
#pragma unroll
        for (int j = 0; j < 4; ++j) r.u[j] = pkman(f[2 * j], f[2 * j + 1]);
        *reinterpret_cast<bf16x8*>(&smem[idx128(REG_A, t, inp * 64 + c0)]) = r.v;
    }
    __syncthreads();                                   // [1]

    // ---- S2: input projection -> X[t][o] (B) ----
    {
        int half = wv >> 1;
        const float* bvec = half ? trans_b : conv_b;
        bf16x8 afr[4][2];
#pragma unroll
        for (int tt = 0; tt < 4; ++tt)
#pragma unroll
            for (int kt = 0; kt < 2; ++kt)
                afr[tt][kt] = *reinterpret_cast<const bf16x8*>(
                    &smem[idx128(REG_A, tt * 16 + col, half * 64 + kt * 32 + quad * 8)]);
#pragma unroll
        for (int otl = 0; otl < 2; ++otl) {
            int rt  = (wv & 1) * 2 + otl;
            int row = rt * 16 + col;
            bf16x8 bfr[2];
#pragma unroll
            for (int kt = 0; kt < 2; ++kt)
                bfr[kt] = *reinterpret_cast<const bf16x8*>(
                    wsW + (half * 512 + (rt * 2 + kt) * 64 + lane) * 8);
            float bias = bvec[row];
            int oc = half * 64 + row;
#pragma unroll
            for (int tt = 0; tt < 4; ++tt) {
                f32x4 acc = {0.f, 0.f, 0.f, 0.f};
#pragma unroll
                for (int kt = 0; kt < 2; ++kt)
                    acc = __builtin_amdgcn_mfma_f32_16x16x32_bf16(afr[tt][kt], bfr[kt], acc, 0, 0, 0);
                unsigned int pA = pkman(acc[0] + bias, acc[1] + bias);
                unsigned int pB = pkman(acc[2] + bias, acc[3] + bias);
                int t0 = tt * 16 + quad * 4;
                smem[idx128(REG_B, t0 + 0, oc)] = (unsigned short)(pA & 0xffff);
                smem[idx128(REG_B, t0 + 1, oc)] = (unsigned short)(pA >> 16);
                smem[idx128(REG_B, t0 + 2, oc)] = (unsigned short)(pB & 0xffff);
                smem[idx128(REG_B, t0 + 3, oc)] = (unsigned short)(pB >> 16);
            }
        }
    }
    __syncthreads();                                   // [2]

    // ---- S3/S4: per-head (wave=head) register-resident attention ----
    {
        const int h = wv;
        const int aA = ((((2 * quad) & 3) << 4) | col) << 2;
        const int aB = ((((2 * quad + 1) & 3) << 4) | col) << 2;
        const bool hiq = quad >= 2;

        // hoisted biases
        float4 qb4[2], kb4[2]; float vb2[2];
#pragma unroll
        for (int dt = 0; dt < 2; ++dt) {
            float4 q = *reinterpret_cast<const float4*>(qkv_b + h * 32 + dt * 16 + quad * 4);
            q.x *= 0.17677669529663689f; q.y *= 0.17677669529663689f;
            q.z *= 0.17677669529663689f; q.w *= 0.17677669529663689f;
            qb4[dt] = q;
            kb4[dt] = *reinterpret_cast<const float4*>(qkv_b + 128 + h * 32 + dt * 16 + quad * 4);
            vb2[dt] = qkv_b[256 + h * 32 + dt * 16 + col];
        }

        bf16x8 qb[4], kb[4], vfr[2][2];

        // V^T: weights hoisted; one a-load per token tile; exchange per tile-pair
        {
            bf16x8 w0[4], w1[4];
#pragma unroll
            for (int kt = 0; kt < 4; ++kt) {
                w0[kt] = *reinterpret_cast<const bf16x8*>(
                    wsW + (1024 + ((16 + 2 * h + 0) * 4 + kt) * 64 + lane) * 8);
                w1[kt] = *reinterpret_cast<const bf16x8*>(
                    wsW + (1024 + ((16 + 2 * h + 1) * 4 + kt) * 64 + lane) * 8);
            }
#pragma unroll
            for (int p = 0; p < 2; ++p) {
                f32x4 vt0[2], vt1[2];
#pragma unroll
                for (int s = 0; s < 2; ++s) {
                    int tt = 2 * p + s;
                    bf16x8 a[4];
#pragma unroll
                    for (int kt = 0; kt < 4; ++kt)
                        a[kt] = *reinterpret_cast<const bf16x8*>(
                            &smem[idx128(REG_B, tt * 16 + col, kt * 32 + quad * 8)]);
                    f32x4 a0 = {0.f, 0.f, 0.f, 0.f}, a1 = {0.f, 0.f, 0.f, 0.f};
#pragma unroll
                    for (int kt = 0; kt < 4; ++kt) {
                        a0 = __builtin_amdgcn_mfma_f32_16x16x32_bf16(a[kt], w0[kt], a0, 0, 0, 0);
                        a1 = __builtin_amdgcn_mfma_f32_16x16x32_bf16(a[kt], w1[kt], a1, 0, 0, 0);
                    }
#pragma unroll
                    for (int g = 0; g < 4; ++g) { a0[g] += vb2[0]; a1[g] += vb2[1]; }
                    vt0[s] = a0; vt1[s] = a1;
                }
                vfr[0][p] = xfrag(vt0[0], vt0[1], aA, aB, hiq);
                vfr[1][p] = xfrag(vt1[0], vt1[1], aA, aB, hiq);
            }
        }

        // Q^T and K^T merged: one a-load per token tile feeds both
#pragma unroll
        for (int t4 = 0; t4 < 4; ++t4) {
            bf16x8 a[4];
#pragma unroll
            for (int kt = 0; kt < 4; ++kt)
                a[kt] = *reinterpret_cast<const bf16x8*>(
                    &smem[idx128(REG_B, t4 * 16 + col, kt * 32 + quad * 8)]);
            f32x4 qa[2], ka[2];
#pragma unroll
            for (int dt = 0; dt < 2; ++dt) {
                bf16x8 w[4];
#pragma unroll
                for (int kt = 0; kt < 4; ++kt)
                    w[kt] = *reinterpret_cast<const bf16x8*>(
                        wsW + (1024 + ((2 * h + dt) * 4 + kt) * 64 + lane) * 8);
                f32x4 acc = {0.f, 0.f, 0.f, 0.f};
#pragma unroll
                for (int kt = 0; kt < 4; ++kt)
                    acc = __builtin_amdgcn_mfma_f32_16x16x32_bf16(w[kt], a[kt], acc, 0, 0, 0);
                acc[0] += qb4[dt].x; acc[1] += qb4[dt].y;
                acc[2] += qb4[dt].z; acc[3] += qb4[dt].w;
                qa[dt] = acc;
#pragma unroll
                for (int kt = 0; kt < 4; ++kt)
                    w[kt] = *reinterpret_cast<const bf16x8*>(
                        wsW + (1024 + ((8 + 2 * h + dt) * 4 + kt) * 64 + lane) * 8);
                f32x4 acck = {0.f, 0.f, 0.f, 0.f};
#pragma unroll
                for (int kt = 0; kt < 4; ++kt)
                    acck = __builtin_amdgcn_mfma_f32_16x16x32_bf16(w[kt], a[kt], acck, 0, 0, 0);
                acck[0] += kb4[dt].x; acck[1] += kb4[dt].y;
                acck[2] += kb4[dt].z; acck[3] += kb4[dt].w;
                ka[dt] = acck;
            }
            qb[t4] = xfrag(qa[0], qa[1], aA, aB, hiq);
            kb[t4] = xfrag(ka[0], ka[1], aA, aB, hiq);
        }

        // S^T (bias as C-init) -> exp -> normalize -> exchange -> PV -> AO (A)
#pragma unroll
        for (int nt = 0; nt < 4; ++nt) {
            f32x4 st[4];
#pragma unroll
            for (int mt = 0; mt < 4; ++mt) {
                f32x4 binit = *reinterpret_cast<const f32x4*>(
                    wsB + ((((h * 4 + mt) * 4 + nt) * 64 + lane) << 2));
                st[mt] = __builtin_amdgcn_mfma_f32_16x16x32_bf16(kb[mt], qb[nt], binit, 0, 0, 0);
            }
            float sm = 0.f;
#pragma unroll
            for (int mt = 0; mt < 4; ++mt)
#pragma unroll
                for (int g = 0; g < 4; ++g) {
                    st[mt][g] = __expf(fminf(st[mt][g], 80.f));
                    sm += st[mt][g];
                }
            sm += __shfl_xor(sm, 16, 64);
            sm += __shfl_xor(sm, 32, 64);
            float inv = 1.0f / sm;
#pragma unroll
            for (int mt = 0; mt < 4; ++mt)
#pragma unroll
                for (int g = 0; g < 4; ++g) st[mt][g] *= inv;
            bf16x8 pa0 = xfrag(st[0], st[1], aA, aB, hiq);
            bf16x8 pa1 = xfrag(st[2], st[3], aA, aB, hiq);
#pragma unroll
            for (int dt = 0; dt < 2; ++dt) {
                f32x4 o = {0.f, 0.f, 0.f, 0.f};
                o = __builtin_amdgcn_mfma_f32_16x16x32_bf16(pa0, vfr[dt][0], o, 0, 0, 0);
                o = __builtin_amdgcn_mfma_f32_16x16x32_bf16(pa1, vfr[dt][1], o, 0, 0, 0);
                int c  = h * 32 + dt * 16 + col;
                int t0 = nt * 16 + quad * 4;
                unsigned int pA = pkman(o[0], o[1]);
                unsigned int pB = pkman(o[2], o[3]);
                smem[idx128(REG_A, t0 + 0, c)] = (unsigned short)(pA & 0xffff);
                smem[idx128(REG_A, t0 + 1, c)] = (unsigned short)(pA >> 16);
                smem[idx128(REG_A, t0 + 2, c)] = (unsigned short)(pB & 0xffff);
                smem[idx128(REG_A, t0 + 3, c)] = (unsigned short)(pB >> 16);
            }
        }
    }
    __syncthreads();                                   // [3]

    // ---- S5: proj + fold halves + bias -> FU[c][t] fp32 (B) ----
    {
        bf16x8 afr[4][4];
#pragma unroll
        for (int tt = 0; tt < 4; ++tt)
#pragma unroll
            for (int kt = 0; kt < 4; ++kt)
                afr[tt][kt] = *reinterpret_cast<const bf16x8*>(
                    &smem[idx128(REG_A, tt * 16 + col, kt * 32 + quad * 8)]);
        int o1 = wv * 16 + col;
        int o2 = 64 + o1;
        bf16x8 b1[4], b2[4];
#pragma unroll
        for (int kt = 0; kt < 4; ++kt) {
            b1[kt] = *reinterpret_cast<const bf16x8*>(wsW + (7168 + (wv * 4 + kt) * 64 + lane) * 8);
            b2[kt] = *reinterpret_cast<const bf16x8*>(wsW + (7168 + ((4 + wv) * 4 + kt) * 64 + lane) * 8);
        }
        float pb = proj_b[o1] + proj_b[o2];
#pragma unroll
        for (int tt = 0; tt < 4; ++tt) {
            f32x4 a1 = {0.f, 0.f, 0.f, 0.f}, a2 = {0.f, 0.f, 0.f, 0.f};
#pragma unroll
            for (int kt = 0; kt < 4; ++kt) {
                a1 = __builtin_amdgcn_mfma_f32_16x16x32_bf16(afr[tt][kt], b1[kt], a1, 0, 0, 0);
                a2 = __builtin_amdgcn_mfma_f32_16x16x32_bf16(afr[tt][kt], b2[kt], a2, 0, 0, 0);
            }
            f32x4 o;
#pragma unroll
            for (int g = 0; g < 4; ++g) o[g] = a1[g] + a2[g] + pb;
            *reinterpret_cast<f32x4*>(&fuf[idxfu(o1, tt * 16 + quad * 4)]) = o;
        }
    }
    __syncthreads();                                   // [4]

    // ---- S6: out = FU + conv_feat residual, coalesced float4 ----
#pragma unroll
    for (int it = 0; it < 4; ++it) {
        int id = tid + (it << 8);       // 0..1023
        int c  = id >> 4;
        int z  = (id >> 2) & 3, y = id & 3;
        int t  = z * 16 + y * 4;
        f32x4 val = *reinterpret_cast<const f32x4*>(&fuf[idxfu(c, t)]);
        f32x4 res = *reinterpret_cast<const f32x4*>(cfeat + (size_t)c * 262144 + vbase + z * 4096 + y * 64);
        f32x4 o;
#pragma unroll
        for (int g = 0; g < 4; ++g) o[g] = val[g] + res[g];
        *reinterpret_cast<f32x4*>(out + (size_t)c * 262144 + vbase + z * 4096 + y * 64) = o;
    }
}

extern "C" void kernel_launch(void* const* d_in, const int* in_sizes, int n_in,
                              void* d_out, int out_size, void* d_ws, size_t ws_size,
                              hipStream_t stream) {
    (void)in_sizes; (void)n_in; (void)out_size; (void)ws_size;
    unsigned short* wsW = (unsigned short*)d_ws;
    float* wsB = (float*)((char*)d_ws + WSB_BYTE_OFF);

    prep_kernel<<<dim3(52), dim3(256), 0, stream>>>(
        (const float*)d_in[2],  // conv_w
        (const float*)d_in[4],  // trans_w
        (const float*)d_in[6],  // qkv_w
        (const float*)d_in[8],  // proj_w
        (const float*)d_in[10], // rel_bias_table
        (const int*)d_in[11],   // rel_index
        wsW, wsB);

    win_attn_kernel<<<dim3(4096), dim3(256), 0, stream>>>(
        (const float*)d_in[0],  // conv_feat
        (const float*)d_in[1],  // transformer_feat
        (const float*)d_in[3],  // conv_b
        (const float*)d_in[5],  // trans_b
        (const float*)d_in[7],  // qkv_b
        (const float*)d_in[9],  // proj_b
        wsW, wsB,
        (float*)d_out);
}

// Round 7
// 314.021 us; speedup vs baseline: 1.5625x; 1.1572x over previous
//
#include <hip/hip_runtime.h>

// SelfAttentionFusion: 3D window attention, WS=4, N=64 tokens/window, C=128, 4 heads x 32.
// 4096 windows, one 256-thread block each. fp32 I/O; bf16 internally for MFMA.
// Round 7: identical structure to round 6; __launch_bounds__(256,2).
// Evidence: this toolchain budgets VGPRs for 2x the declared waves/EU
// ((256,4)->64 VGPR, (256,3)->84 VGPR) => (256,2) -> 128-VGPR budget, which fits
// the ~110 VGPRs of live fragment state and kills the ~193 MB/dispatch spill-store
// traffic seen in WRITE_SIZE.

typedef __attribute__((ext_vector_type(8))) short bf16x8;
typedef __attribute__((ext_vector_type(4))) float f32x4;

__device__ __forceinline__ unsigned short f2b(float f) {
    union { float f; unsigned int i; } v; v.f = f;
    unsigned int i = v.i;
    return (unsigned short)((i + 0x7FFFu + ((i >> 16) & 1u)) >> 16);
}
// pack bf16(a) in low16, bf16(b) in high16 (verified manual RNE)
__device__ __forceinline__ unsigned int pkman(float a, float b) {
    return ((unsigned int)f2b(b) << 16) | (unsigned int)f2b(a);
}

union U8 { bf16x8 v; unsigned int u[4]; };

// Quad-exchange: C-frags (lo: rows 0..15, hi: rows 16..31 of a 32-row block,
// row = 16*(hi) + 4*quad + g, col = lane&15) -> A/B-frag (m/n = lane&15,
// element j holds row k = 8*quad + j). HW-verified (round 5/6 passed).
__device__ __forceinline__ bf16x8 xfrag(const f32x4 lo, const f32x4 hi,
                                        int aA, int aB, bool hiq) {
    unsigned int l0 = pkman(lo[0], lo[1]), l1 = pkman(lo[2], lo[3]);
    unsigned int h0 = pkman(hi[0], hi[1]), h1 = pkman(hi[2], hi[3]);
    U8 r;
    unsigned int tl, th;
    tl = (unsigned int)__builtin_amdgcn_ds_bpermute(aA, (int)l0);
    th = (unsigned int)__builtin_amdgcn_ds_bpermute(aA, (int)h0);
    r.u[0] = hiq ? th : tl;
    tl = (unsigned int)__builtin_amdgcn_ds_bpermute(aA, (int)l1);
    th = (unsigned int)__builtin_amdgcn_ds_bpermute(aA, (int)h1);
    r.u[1] = hiq ? th : tl;
    tl = (unsigned int)__builtin_amdgcn_ds_bpermute(aB, (int)l0);
    th = (unsigned int)__builtin_amdgcn_ds_bpermute(aB, (int)h0);
    r.u[2] = hiq ? th : tl;
    tl = (unsigned int)__builtin_amdgcn_ds_bpermute(aB, (int)l1);
    th = (unsigned int)__builtin_amdgcn_ds_bpermute(aB, (int)h1);
    r.u[3] = hiq ? th : tl;
    return r.v;
}

// ---- workspace layout ----
// wsW (ushort): fragment-ordered bf16 weights, group = 64 lanes x 8 elems per tile
//   conv [0,512) trans [512,1024) qkv [1024,7168) (q rows prescaled) proj [7168,9216)
// wsB (float @byte 147456): bias C-frags for S^T: [h][mt][nt][lane]*4
#define WSB_BYTE_OFF 147456

__global__ __launch_bounds__(256) void prep_kernel(
    const float* __restrict__ conv_w, const float* __restrict__ trans_w,
    const float* __restrict__ qkv_w, const float* __restrict__ proj_w,
    const float* __restrict__ btab, const int* __restrict__ ridx,
    unsigned short* __restrict__ wsW, float* __restrict__ wsB)
{
    int id = blockIdx.x * 256 + threadIdx.x;
    if (id < 9216) {
        int lane = id & 63;
        int colr = lane & 15, quad = lane >> 4;
        const float* src;
        float scale = 1.0f;
        if (id < 512) {
            int tile = id >> 6; int rt = tile >> 1, kt = tile & 1;
            src = conv_w + (rt * 16 + colr) * 64 + kt * 32 + quad * 8;
        } else if (id < 1024) {
            int tile = (id - 512) >> 6; int rt = tile >> 1, kt = tile & 1;
            src = trans_w + (rt * 16 + colr) * 64 + kt * 32 + quad * 8;
        } else if (id < 7168) {
            int tile = (id - 1024) >> 6; int rt = tile >> 2, kt = tile & 3;
            int r = rt * 16 + colr;
            src = qkv_w + r * 128 + kt * 32 + quad * 8;
            if (r < 128) scale = 0.17677669529663689f;  // fold hd^-0.5 into q weights
        } else {
            int tile = (id - 7168) >> 6; int rt = tile >> 2, kt = tile & 3;
            src = proj_w + (rt * 16 + colr) * 128 + kt * 32 + quad * 8;
        }
        bf16x8 r;
#pragma unroll
        for (int j = 0; j < 8; ++j) r[j] = (short)f2b(src[j] * scale);
        *reinterpret_cast<bf16x8*>(wsW + id * 8) = r;
    } else if (id < 13312) {
        int i = id - 9216;                        // 0..4095
        int h = i >> 10, mt = (i >> 8) & 3, nt = (i >> 6) & 3, lane = i & 63;
        int colr = lane & 15, quad = lane >> 4;
        f32x4 o;
#pragma unroll
        for (int g = 0; g < 4; ++g) {
            int n = nt * 16 + colr;               // query token
            int m = mt * 16 + quad * 4 + g;       // key token (S^T row)
            o[g] = btab[ridx[n * 64 + m] * 4 + h];
        }
        *reinterpret_cast<f32x4*>(wsB + i * 4) = o;
    }
}

// ---- LDS: 2 regions of 8192 ushorts (32 KB) ----
// A [0,8192):     XIN[t][128] -> AO[t][128]
// B [8192,16384): X[t][128]   -> FU[c][64] (fp32)
#define REG_A 0
#define REG_B 8192

__device__ __forceinline__ int idx128(int base, int t, int c) {
    int swz = ((c >> 3) ^ (t & 15)) & 15;
    return base + t * 128 + (swz << 3) + (c & 7);
}
__device__ __forceinline__ int idxfu(int c, int t) {
    int swz = ((t >> 2) ^ (c & 15)) & 15;
    return c * 64 + (swz << 2) + (t & 3);
}

__global__ __launch_bounds__(256, 2) void win_attn_kernel(
    const float* __restrict__ cfeat,
    const float* __restrict__ tfeat,
    const float* __restrict__ conv_b,
    const float* __restrict__ trans_b,
    const float* __restrict__ qkv_b,
    const float* __restrict__ proj_b,
    const unsigned short* __restrict__ wsW,
    const float* __restrict__ wsB,
    float* __restrict__ out)
{
    __shared__ unsigned short smem[16384];  // 32 KB
    float* fuf = reinterpret_cast<float*>(&smem[REG_B]);

    const int tid  = threadIdx.x;
    const int lane = tid & 63;
    const int wv   = tid >> 6;
    const int col  = lane & 15;
    const int quad = lane >> 4;

    // XCD swizzle: consecutive same-XCD dispatch slots get consecutive wx -> L2 sharing
    int b   = blockIdx.x;
    int wid = ((b & 7) << 9) | (b >> 3);
    int wz = wid >> 8, wy = (wid >> 4) & 15, wx = wid & 15;
    const int vbase = wz * 16384 + wy * 256 + wx * 4;

    // ---- S1: global fp32 -> bf16 XIN[t][cc] (A) via b128 writes ----
#pragma unroll
    for (int it = 0; it < 4; ++it) {
        int id = tid + (it << 8);          // 0..1023
        int cg = id >> 6;                  // 16 chunks (8 conv, 8 trans)
        int t  = id & 63;
        int inp = cg >> 3;
        int c0  = (cg & 7) << 3;
        const float* src = (inp ? tfeat : cfeat) + (size_t)c0 * 262144 + vbase
                         + ((t >> 4) << 12) + (((t >> 2) & 3) << 6) + (t & 3);
        float f[8];
#pragma unroll
        for (int j = 0; j < 8; ++j) f[j] = src[(size_t)j * 262144];
        U8 r;
#pragma unroll
        for (int j = 0; j < 4; ++j) r.u[j] = pkman(f[2 * j], f[2 * j + 1]);
        *reinterpret_cast<bf16x8*>(&smem[idx128(REG_A, t, inp * 64 + c0)]) = r.v;
    }
    __syncthreads();                                   // [1]

    // ---- S2: input projection -> X[t][o] (B) ----
    {
        int half = wv >> 1;
        const float* bvec = half ? trans_b : conv_b;
        bf16x8 afr[4][2];
#pragma unroll
        for (int tt = 0; tt < 4; ++tt)
#pragma unroll
            for (int kt = 0; kt < 2; ++kt)
                afr[tt][kt] = *reinterpret_cast<const bf16x8*>(
                    &smem[idx128(REG_A, tt * 16 + col, half * 64 + kt * 32 + quad * 8)]);
#pragma unroll
        for (int otl = 0; otl < 2; ++otl) {
            int rt  = (wv & 1) * 2 + otl;
            int row = rt * 16 + col;
            bf16x8 bfr[2];
#pragma unroll
            for (int kt = 0; kt < 2; ++kt)
                bfr[kt] = *reinterpret_cast<const bf16x8*>(
                    wsW + (half * 512 + (rt * 2 + kt) * 64 + lane) * 8);
            float bias = bvec[row];
            int oc = half * 64 + row;
#pragma unroll
            for (int tt = 0; tt < 4; ++tt) {
                f32x4 acc = {0.f, 0.f, 0.f, 0.f};
#pragma unroll
                for (int kt = 0; kt < 2; ++kt)
                    acc = __builtin_amdgcn_mfma_f32_16x16x32_bf16(afr[tt][kt], bfr[kt], acc, 0, 0, 0);
                unsigned int pA = pkman(acc[0] + bias, acc[1] + bias);
                unsigned int pB = pkman(acc[2] + bias, acc[3] + bias);
                int t0 = tt * 16 + quad * 4;
                smem[idx128(REG_B, t0 + 0, oc)] = (unsigned short)(pA & 0xffff);
                smem[idx128(REG_B, t0 + 1, oc)] = (unsigned short)(pA >> 16);
                smem[idx128(REG_B, t0 + 2, oc)] = (unsigned short)(pB & 0xffff);
                smem[idx128(REG_B, t0 + 3, oc)] = (unsigned short)(pB >> 16);
            }
        }
    }
    __syncthreads();                                   // [2]

    // ---- S3/S4: per-head (wave=head) register-resident attention ----
    {
        const int h = wv;
        const int aA = ((((2 * quad) & 3) << 4) | col) << 2;
        const int aB = ((((2 * quad + 1) & 3) << 4) | col) << 2;
        const bool hiq = quad >= 2;

        // hoisted biases
        float4 qb4[2], kb4[2]; float vb2[2];
#pragma unroll
        for (int dt = 0; dt < 2; ++dt) {
            float4 q = *reinterpret_cast<const float4*>(qkv_b + h * 32 + dt * 16 + quad * 4);
            q.x *= 0.17677669529663689f; q.y *= 0.17677669529663689f;
            q.z *= 0.17677669529663689f; q.w *= 0.17677669529663689f;
            qb4[dt] = q;
            kb4[dt] = *reinterpret_cast<const float4*>(qkv_b + 128 + h * 32 + dt * 16 + quad * 4);
            vb2[dt] = qkv_b[256 + h * 32 + dt * 16 + col];
        }

        bf16x8 qb[4], kb[4], vfr[2][2];

        // V^T: weights hoisted; one a-load per token tile; exchange per tile-pair
        {
            bf16x8 w0[4], w1[4];
#pragma unroll
            for (int kt = 0; kt < 4; ++kt) {
                w0[kt] = *reinterpret_cast<const bf16x8*>(
                    wsW + (1024 + ((16 + 2 * h + 0) * 4 + kt) * 64 + lane) * 8);
                w1[kt] = *reinterpret_cast<const bf16x8*>(
                    wsW + (1024 + ((16 + 2 * h + 1) * 4 + kt) * 64 + lane) * 8);
            }
#pragma unroll
            for (int p = 0; p < 2; ++p) {
                f32x4 vt0[2], vt1[2];
#pragma unroll
                for (int s = 0; s < 2; ++s) {
                    int tt = 2 * p + s;
                    bf16x8 a[4];
#pragma unroll
                    for (int kt = 0; kt < 4; ++kt)
                        a[kt] = *reinterpret_cast<const bf16x8*>(
                            &smem[idx128(REG_B, tt * 16 + col, kt * 32 + quad * 8)]);
                    f32x4 a0 = {0.f, 0.f, 0.f, 0.f}, a1 = {0.f, 0.f, 0.f, 0.f};
#pragma unroll
                    for (int kt = 0; kt < 4; ++kt) {
                        a0 = __builtin_amdgcn_mfma_f32_16x16x32_bf16(a[kt], w0[kt], a0, 0, 0, 0);
                        a1 = __builtin_amdgcn_mfma_f32_16x16x32_bf16(a[kt], w1[kt], a1, 0, 0, 0);
                    }
#pragma unroll
                    for (int g = 0; g < 4; ++g) { a0[g] += vb2[0]; a1[g] += vb2[1]; }
                    vt0[s] = a0; vt1[s] = a1;
                }
                vfr[0][p] = xfrag(vt0[0], vt0[1], aA, aB, hiq);
                vfr[1][p] = xfrag(vt1[0], vt1[1], aA, aB, hiq);
            }
        }

        // Q^T and K^T merged: one a-load per token tile feeds both
#pragma unroll
        for (int t4 = 0; t4 < 4; ++t4) {
            bf16x8 a[4];
#pragma unroll
            for (int kt = 0; kt < 4; ++kt)
                a[kt] = *reinterpret_cast<const bf16x8*>(
                    &smem[idx128(REG_B, t4 * 16 + col, kt * 32 + quad * 8)]);
            f32x4 qa[2], ka[2];
#pragma unroll
            for (int dt = 0; dt < 2; ++dt) {
                bf16x8 w[4];
#pragma unroll
                for (int kt = 0; kt < 4; ++kt)
                    w[kt] = *reinterpret_cast<const bf16x8*>(
                        wsW + (1024 + ((2 * h + dt) * 4 + kt) * 64 + lane) * 8);
                f32x4 acc = {0.f, 0.f, 0.f, 0.f};
#pragma unroll
                for (int kt = 0; kt < 4; ++kt)
                    acc = __builtin_amdgcn_mfma_f32_16x16x32_bf16(w[kt], a[kt], acc, 0, 0, 0);
                acc[0] += qb4[dt].x; acc[1] += qb4[dt].y;
                acc[2] += qb4[dt].z; acc[3] += qb4[dt].w;
                qa[dt] = acc;
#pragma unroll
                for (int kt = 0; kt < 4; ++kt)
                    w[kt] = *reinterpret_cast<const bf16x8*>(
                        wsW + (1024 + ((8 + 2 * h + dt) * 4 + kt) * 64 + lane) * 8);
                f32x4 acck = {0.f, 0.f, 0.f, 0.f};
#pragma unroll
                for (int kt = 0; kt < 4; ++kt)
                    acck = __builtin_amdgcn_mfma_f32_16x16x32_bf16(w[kt], a[kt], acck, 0, 0, 0);
                acck[0] += kb4[dt].x; acck[1] += kb4[dt].y;
                acck[2] += kb4[dt].z; acck[3] += kb4[dt].w;
                ka[dt] = acck;
            }
            qb[t4] = xfrag(qa[0], qa[1], aA, aB, hiq);
            kb[t4] = xfrag(ka[0], ka[1], aA, aB, hiq);
        }

        // S^T (bias as C-init) -> exp -> normalize -> exchange -> PV -> AO (A)
#pragma unroll
        for (int nt = 0; nt < 4; ++nt) {
            f32x4 st[4];
#pragma unroll
            for (int mt = 0; mt < 4; ++mt) {
                f32x4 binit = *reinterpret_cast<const f32x4*>(
                    wsB + ((((h * 4 + mt) * 4 + nt) * 64 + lane) << 2));
                st[mt] = __builtin_amdgcn_mfma_f32_16x16x32_bf16(kb[mt], qb[nt], binit, 0, 0, 0);
            }
            float sm = 0.f;
#pragma unroll
            for (int mt = 0; mt < 4; ++mt)
#pragma unroll
                for (int g = 0; g < 4; ++g) {
                    st[mt][g] = __expf(fminf(st[mt][g], 80.f));
                    sm += st[mt][g];
                }
            sm += __shfl_xor(sm, 16, 64);
            sm += __shfl_xor(sm, 32, 64);
            float inv = 1.0f / sm;
#pragma unroll
            for (int mt = 0; mt < 4; ++mt)
#pragma unroll
                for (int g = 0; g < 4; ++g) st[mt][g] *= inv;
            bf16x8 pa0 = xfrag(st[0], st[1], aA, aB, hiq);
            bf16x8 pa1 = xfrag(st[2], st[3], aA, aB, hiq);
#pragma unroll
            for (int dt = 0; dt < 2; ++dt) {
                f32x4 o = {0.f, 0.f, 0.f, 0.f};
                o = __builtin_amdgcn_mfma_f32_16x16x32_bf16(pa0, vfr[dt][0], o, 0, 0, 0);
                o = __builtin_amdgcn_mfma_f32_16x16x32_bf16(pa1, vfr[dt][1], o, 0, 0, 0);
                int c  = h * 32 + dt * 16 + col;
                int t0 = nt * 16 + quad * 4;
                unsigned int pA = pkman(o[0], o[1]);
                unsigned int pB = pkman(o[2], o[3]);
                smem[idx128(REG_A, t0 + 0, c)] = (unsigned short)(pA & 0xffff);
                smem[idx128(REG_A, t0 + 1, c)] = (unsigned short)(pA >> 16);
                smem[idx128(REG_A, t0 + 2, c)] = (unsigned short)(pB & 0xffff);
                smem[idx128(REG_A, t0 + 3, c)] = (unsigned short)(pB >> 16);
            }
        }
    }
    __syncthreads();                                   // [3]

    // ---- S5: proj + fold halves + bias -> FU[c][t] fp32 (B) ----
    {
        bf16x8 afr[4][4];
#pragma unroll
        for (int tt = 0; tt < 4; ++tt)
#pragma unroll
            for (int kt = 0; kt < 4; ++kt)
                afr[tt][kt] = *reinterpret_cast<const bf16x8*>(
                    &smem[idx128(REG_A, tt * 16 + col, kt * 32 + quad * 8)]);
        int o1 = wv * 16 + col;
        int o2 = 64 + o1;
        bf16x8 b1[4], b2[4];
#pragma unroll
        for (int kt = 0; kt < 4; ++kt) {
            b1[kt] = *reinterpret_cast<const bf16x8*>(wsW + (7168 + (wv * 4 + kt) * 64 + lane) * 8);
            b2[kt] = *reinterpret_cast<const bf16x8*>(wsW + (7168 + ((4 + wv) * 4 + kt) * 64 + lane) * 8);
        }
        float pb = proj_b[o1] + proj_b[o2];
#pragma unroll
        for (int tt = 0; tt < 4; ++tt) {
            f32x4 a1 = {0.f, 0.f, 0.f, 0.f}, a2 = {0.f, 0.f, 0.f, 0.f};
#pragma unroll
            for (int kt = 0; kt < 4; ++kt) {
                a1 = __builtin_amdgcn_mfma_f32_16x16x32_bf16(afr[tt][kt], b1[kt], a1, 0, 0, 0);
                a2 = __builtin_amdgcn_mfma_f32_16x16x32_bf16(afr[tt][kt], b2[kt], a2, 0, 0, 0);
            }
            f32x4 o;
#pragma unroll
            for (int g = 0; g < 4; ++g) o[g] = a1[g] + a2[g] + pb;
            *reinterpret_cast<f32x4*>(&fuf[idxfu(o1, tt * 16 + quad * 4)]) = o;
        }
    }
    __syncthreads();                                   // [4]

    // ---- S6: out = FU + conv_feat residual, coalesced float4 ----
#pragma unroll
    for (int it = 0; it < 4; ++it) {
        int id = tid + (it << 8);       // 0..1023
        int c  = id >> 4;
        int z  = (id >> 2) & 3, y = id & 3;
        int t  = z * 16 + y * 4;
        f32x4 val = *reinterpret_cast<const f32x4*>(&fuf[idxfu(c, t)]);
        f32x4 res = *reinterpret_cast<const f32x4*>(cfeat + (size_t)c * 262144 + vbase + z * 4096 + y * 64);
        f32x4 o;
#pragma unroll
        for (int g = 0; g < 4; ++g) o[g] = val[g] + res[g];
        *reinterpret_cast<f32x4*>(out + (size_t)c * 262144 + vbase + z * 4096 + y * 64) = o;
    }
}

extern "C" void kernel_launch(void* const* d_in, const int* in_sizes, int n_in,
                              void* d_out, int out_size, void* d_ws, size_t ws_size,
                              hipStream_t stream) {
    (void)in_sizes; (void)n_in; (void)out_size; (void)ws_size;
    unsigned short* wsW = (unsigned short*)d_ws;
    float* wsB = (float*)((char*)d_ws + WSB_BYTE_OFF);

    prep_kernel<<<dim3(52), dim3(256), 0, stream>>>(
        (const float*)d_in[2],  // conv_w
        (const float*)d_in[4],  // trans_w
        (const float*)d_in[6],  // qkv_w
        (const float*)d_in[8],  // proj_w
        (const float*)d_in[10], // rel_bias_table
        (const int*)d_in[11],   // rel_index
        wsW, wsB);

    win_attn_kernel<<<dim3(4096), dim3(256), 0, stream>>>(
        (const float*)d_in[0],  // conv_feat
        (const float*)d_in[1],  // transformer_feat
        (const float*)d_in[3],  // conv_b
        (const float*)d_in[5],  // trans_b
        (const float*)d_in[7],  // qkv_b
        (const float*)d_in[9],  // proj_b
        wsW, wsB,
        (float*)d_out);
}